// Round 1
// baseline (1980.010 us; speedup 1.0000x reference)
//
#include <hip/hip_runtime.h>
#include <hip/hip_bf16.h>

#define N_NODES 100000
#define N_EDGES 3200000
#define DIM0 512   // IN_DIM * N_SEQ
#define DIM1 256   // HID1
#define DIM2 128   // HID2
#define DIM3 64    // END

// ---------------- CSR build ----------------

__global__ __launch_bounds__(256) void k_hist(const int* __restrict__ src,
                                              const int* __restrict__ dst,
                                              int* __restrict__ cnt_out,
                                              int* __restrict__ cnt_in,
                                              int* __restrict__ pos) {
    int e = blockIdx.x * 256 + threadIdx.x;
    if (e < N_EDGES) {
        atomicAdd(&cnt_out[src[e]], 1);
        pos[e] = atomicAdd(&cnt_in[dst[e]], 1);
    }
}

// single-block exclusive scan of cnt_in -> row_ptr (row_ptr[N]=total)
__global__ __launch_bounds__(1024) void k_scan(const int* __restrict__ cnt,
                                               int* __restrict__ row_ptr) {
    __shared__ int buf[1024];
    int tid = threadIdx.x;
    int carry = 0;
    for (int base = 0; base < N_NODES; base += 1024) {
        int i = base + tid;
        int v = (i < N_NODES) ? cnt[i] : 0;
        buf[tid] = v;
        __syncthreads();
        #pragma unroll
        for (int off = 1; off < 1024; off <<= 1) {
            int t = (tid >= off) ? buf[tid - off] : 0;
            __syncthreads();
            buf[tid] += t;
            __syncthreads();
        }
        int incl = buf[tid];
        if (i < N_NODES) row_ptr[i] = carry + incl - v;
        carry += buf[1023];
        __syncthreads();
    }
    if (tid == 0) row_ptr[N_NODES] = carry;
}

__global__ __launch_bounds__(256) void k_scatter(const int* __restrict__ src,
                                                 const int* __restrict__ dst,
                                                 const int* __restrict__ row_ptr,
                                                 const int* __restrict__ pos,
                                                 int* __restrict__ esrc) {
    int e = blockIdx.x * 256 + threadIdx.x;
    if (e < N_EDGES) esrc[row_ptr[dst[e]] + pos[e]] = src[e];
}

__global__ __launch_bounds__(256) void k_scales(const int* __restrict__ cnt_out,
                                                const int* __restrict__ cnt_in,
                                                float* __restrict__ s_out,
                                                float* __restrict__ s_in) {
    int i = blockIdx.x * 256 + threadIdx.x;
    if (i < N_NODES) {
        int co = cnt_out[i]; if (co < 1) co = 1;
        int ci = cnt_in[i];  if (ci < 1) ci = 1;
        s_out[i] = rsqrtf((float)co);
        s_in[i]  = rsqrtf((float)ci);
    }
}

// ---------------- GEMM1: y1 = (feat * s_out) @ W1   [N,512]x[512,256] ----------------
// 64x64 tile, BK=16, 256 threads, 4x4 per thread

__global__ __launch_bounds__(256) void k_gemm1(const float* __restrict__ feat,
                                               const float* __restrict__ s_out,
                                               const float* __restrict__ W,
                                               float* __restrict__ y) {
    __shared__ float As[16][65];   // [k][n]
    __shared__ float Bs[16][64];   // [k][m]
    int tid = threadIdx.x;
    int tx = tid & 15, ty = tid >> 4;
    int n0 = blockIdx.y * 64;
    int m0 = blockIdx.x * 64;

    int arow = tid >> 2, acol0 = (tid & 3) * 4;
    int an = n0 + arow;
    float ascale = (an < N_NODES) ? s_out[an] : 0.0f;
    int an_c = (an < N_NODES) ? an : (N_NODES - 1);
    const float* aptr = feat + (size_t)an_c * DIM0 + acol0;
    const float* bptr = W + ty * DIM1 + m0 + tx * 4;

    float c[4][4] = {};
    for (int k0 = 0; k0 < DIM0; k0 += 16) {
        float4 av = *(const float4*)(aptr + k0);
        float4 bv = *(const float4*)(bptr + (size_t)k0 * DIM1);
        __syncthreads();
        As[acol0 + 0][arow] = av.x * ascale;
        As[acol0 + 1][arow] = av.y * ascale;
        As[acol0 + 2][arow] = av.z * ascale;
        As[acol0 + 3][arow] = av.w * ascale;
        *(float4*)&Bs[ty][tx * 4] = bv;
        __syncthreads();
        #pragma unroll
        for (int k = 0; k < 16; ++k) {
            float a0 = As[k][ty * 4 + 0];
            float a1 = As[k][ty * 4 + 1];
            float a2 = As[k][ty * 4 + 2];
            float a3 = As[k][ty * 4 + 3];
            float4 b = *(const float4*)&Bs[k][tx * 4];
            c[0][0] += a0 * b.x; c[0][1] += a0 * b.y; c[0][2] += a0 * b.z; c[0][3] += a0 * b.w;
            c[1][0] += a1 * b.x; c[1][1] += a1 * b.y; c[1][2] += a1 * b.z; c[1][3] += a1 * b.w;
            c[2][0] += a2 * b.x; c[2][1] += a2 * b.y; c[2][2] += a2 * b.z; c[2][3] += a2 * b.w;
            c[3][0] += a3 * b.x; c[3][1] += a3 * b.y; c[3][2] += a3 * b.z; c[3][3] += a3 * b.w;
        }
    }
    #pragma unroll
    for (int i = 0; i < 4; ++i) {
        int n = n0 + ty * 4 + i;
        if (n < N_NODES) {
            float4 v = make_float4(c[i][0], c[i][1], c[i][2], c[i][3]);
            *(float4*)&y[(size_t)n * DIM1 + m0 + tx * 4] = v;
        }
    }
}

// ---------------- aggregation dim=256: one wave per dst node ----------------

__global__ __launch_bounds__(256) void k_agg256(const int* __restrict__ row_ptr,
                                                const int* __restrict__ esrc,
                                                const float* __restrict__ y1,
                                                float* __restrict__ agg) {
    int wave = threadIdx.x >> 6;
    int lane = threadIdx.x & 63;
    int n = blockIdx.x * 4 + wave;   // 25000 blocks * 4 = 100000 exact
    int beg = row_ptr[n], end = row_ptr[n + 1];
    float4 acc = make_float4(0.f, 0.f, 0.f, 0.f);
    int i = beg;
    for (; i + 4 <= end; i += 4) {
        int s0 = esrc[i], s1 = esrc[i + 1], s2 = esrc[i + 2], s3 = esrc[i + 3];
        float4 v0 = *(const float4*)&y1[(size_t)s0 * DIM1 + lane * 4];
        float4 v1 = *(const float4*)&y1[(size_t)s1 * DIM1 + lane * 4];
        float4 v2 = *(const float4*)&y1[(size_t)s2 * DIM1 + lane * 4];
        float4 v3 = *(const float4*)&y1[(size_t)s3 * DIM1 + lane * 4];
        acc.x += v0.x + v1.x + v2.x + v3.x;
        acc.y += v0.y + v1.y + v2.y + v3.y;
        acc.z += v0.z + v1.z + v2.z + v3.z;
        acc.w += v0.w + v1.w + v2.w + v3.w;
    }
    for (; i < end; ++i) {
        int s = esrc[i];
        float4 v = *(const float4*)&y1[(size_t)s * DIM1 + lane * 4];
        acc.x += v.x; acc.y += v.y; acc.z += v.z; acc.w += v.w;
    }
    *(float4*)&agg[(size_t)n * DIM1 + lane * 4] = acc;
}

// ---------------- GEMM2: y2 = (relu(agg1*s_in+b1) * s_out) @ W2  [N,256]x[256,128] ----

__global__ __launch_bounds__(256) void k_gemm2(const float* __restrict__ agg1,
                                               const float* __restrict__ s_in,
                                               const float* __restrict__ s_out,
                                               const float* __restrict__ b1,
                                               const float* __restrict__ W,
                                               float* __restrict__ y) {
    __shared__ float As[16][65];
    __shared__ float Bs[16][64];
    int tid = threadIdx.x;
    int tx = tid & 15, ty = tid >> 4;
    int n0 = blockIdx.y * 64;
    int m0 = blockIdx.x * 64;

    int arow = tid >> 2, acol0 = (tid & 3) * 4;
    int an = n0 + arow;
    bool valid = (an < N_NODES);
    int an_c = valid ? an : (N_NODES - 1);
    float si = valid ? s_in[an] : 0.0f;
    float so = valid ? s_out[an] : 0.0f;
    const float* aptr = agg1 + (size_t)an_c * DIM1 + acol0;
    const float* bptr = W + ty * DIM2 + m0 + tx * 4;

    float c[4][4] = {};
    for (int k0 = 0; k0 < DIM1; k0 += 16) {
        float4 av = *(const float4*)(aptr + k0);
        float4 bb = *(const float4*)(b1 + k0 + acol0);
        float4 bv = *(const float4*)(bptr + (size_t)k0 * DIM2);
        av.x = fmaxf(av.x * si + bb.x, 0.f) * so;
        av.y = fmaxf(av.y * si + bb.y, 0.f) * so;
        av.z = fmaxf(av.z * si + bb.z, 0.f) * so;
        av.w = fmaxf(av.w * si + bb.w, 0.f) * so;
        __syncthreads();
        As[acol0 + 0][arow] = av.x;
        As[acol0 + 1][arow] = av.y;
        As[acol0 + 2][arow] = av.z;
        As[acol0 + 3][arow] = av.w;
        *(float4*)&Bs[ty][tx * 4] = bv;
        __syncthreads();
        #pragma unroll
        for (int k = 0; k < 16; ++k) {
            float a0 = As[k][ty * 4 + 0];
            float a1 = As[k][ty * 4 + 1];
            float a2 = As[k][ty * 4 + 2];
            float a3 = As[k][ty * 4 + 3];
            float4 b = *(const float4*)&Bs[k][tx * 4];
            c[0][0] += a0 * b.x; c[0][1] += a0 * b.y; c[0][2] += a0 * b.z; c[0][3] += a0 * b.w;
            c[1][0] += a1 * b.x; c[1][1] += a1 * b.y; c[1][2] += a1 * b.z; c[1][3] += a1 * b.w;
            c[2][0] += a2 * b.x; c[2][1] += a2 * b.y; c[2][2] += a2 * b.z; c[2][3] += a2 * b.w;
            c[3][0] += a3 * b.x; c[3][1] += a3 * b.y; c[3][2] += a3 * b.z; c[3][3] += a3 * b.w;
        }
    }
    #pragma unroll
    for (int i = 0; i < 4; ++i) {
        int n = n0 + ty * 4 + i;
        if (n < N_NODES) {
            float4 v = make_float4(c[i][0], c[i][1], c[i][2], c[i][3]);
            *(float4*)&y[(size_t)n * DIM2 + m0 + tx * 4] = v;
        }
    }
}

// ---------------- aggregation dim=128 ----------------

__global__ __launch_bounds__(256) void k_agg128(const int* __restrict__ row_ptr,
                                                const int* __restrict__ esrc,
                                                const float* __restrict__ y2,
                                                float* __restrict__ agg) {
    int wave = threadIdx.x >> 6;
    int lane = threadIdx.x & 63;
    int n = blockIdx.x * 4 + wave;
    int beg = row_ptr[n], end = row_ptr[n + 1];
    float2 acc = make_float2(0.f, 0.f);
    int i = beg;
    for (; i + 4 <= end; i += 4) {
        int s0 = esrc[i], s1 = esrc[i + 1], s2 = esrc[i + 2], s3 = esrc[i + 3];
        float2 v0 = *(const float2*)&y2[(size_t)s0 * DIM2 + lane * 2];
        float2 v1 = *(const float2*)&y2[(size_t)s1 * DIM2 + lane * 2];
        float2 v2 = *(const float2*)&y2[(size_t)s2 * DIM2 + lane * 2];
        float2 v3 = *(const float2*)&y2[(size_t)s3 * DIM2 + lane * 2];
        acc.x += v0.x + v1.x + v2.x + v3.x;
        acc.y += v0.y + v1.y + v2.y + v3.y;
    }
    for (; i < end; ++i) {
        int s = esrc[i];
        float2 v = *(const float2*)&y2[(size_t)s * DIM2 + lane * 2];
        acc.x += v.x; acc.y += v.y;
    }
    *(float2*)&agg[(size_t)n * DIM2 + lane * 2] = acc;
}

// ---------------- head: out = relu((agg2*s_in+b2)@Wo1+bo1)@Wo2+bo2 ----------------

__global__ __launch_bounds__(256) void k_head(const float* __restrict__ agg2,
                                              const float* __restrict__ s_in,
                                              const float* __restrict__ b2,
                                              const float* __restrict__ Wo1,
                                              const float* __restrict__ bo1,
                                              const float* __restrict__ Wo2,
                                              const float* __restrict__ bo2,
                                              float* __restrict__ out) {
    __shared__ float w1s[DIM2 * DIM3];   // 32 KB
    __shared__ float w2s[DIM3];
    __shared__ float hs[4][DIM2];
    int tid = threadIdx.x;
    for (int i = tid; i < DIM2 * DIM3; i += 256) w1s[i] = Wo1[i];
    if (tid < DIM3) w2s[tid] = Wo2[tid];
    int wave = tid >> 6, lane = tid & 63;
    int n = blockIdx.x * 4 + wave;
    float si = s_in[n];
    float2 hv = *(const float2*)&agg2[(size_t)n * DIM2 + lane * 2];
    float2 bv = *(const float2*)&b2[lane * 2];
    hs[wave][lane * 2 + 0] = hv.x * si + bv.x;
    hs[wave][lane * 2 + 1] = hv.y * si + bv.y;
    __syncthreads();
    float t = bo1[lane];
    #pragma unroll 8
    for (int k = 0; k < DIM2; ++k) t += hs[wave][k] * w1s[k * DIM3 + lane];
    t = fmaxf(t, 0.f);
    float p = t * w2s[lane];
    #pragma unroll
    for (int off = 32; off > 0; off >>= 1) p += __shfl_down(p, off);
    if (lane == 0) out[n] = p + bo2[0];
}

// ---------------- launch ----------------

extern "C" void kernel_launch(void* const* d_in, const int* in_sizes, int n_in,
                              void* d_out, int out_size, void* d_ws, size_t ws_size,
                              hipStream_t stream) {
    const float* feat = (const float*)d_in[0];
    const int*   src  = (const int*)d_in[1];
    const int*   dst  = (const int*)d_in[2];
    const float* W1   = (const float*)d_in[3];
    const float* b1   = (const float*)d_in[4];
    const float* W2   = (const float*)d_in[5];
    const float* b2   = (const float*)d_in[6];
    const float* Wo1  = (const float*)d_in[7];
    const float* bo1  = (const float*)d_in[8];
    const float* Wo2  = (const float*)d_in[9];
    const float* bo2  = (const float*)d_in[10];
    float* out = (float*)d_out;

    char* ws = (char*)d_ws;
    size_t off = 0;
    auto alloc = [&](size_t bytes) -> char* {
        char* p = ws + off;
        off = (off + bytes + 255) & ~(size_t)255;
        return p;
    };
    int*   cnt_out = (int*)alloc(N_NODES * 4);
    int*   cnt_in  = (int*)alloc(N_NODES * 4);
    int*   row_ptr = (int*)alloc((N_NODES + 1) * 4);
    int*   pos     = (int*)alloc((size_t)N_EDGES * 4);
    int*   esrc    = (int*)alloc((size_t)N_EDGES * 4);
    float* s_out   = (float*)alloc(N_NODES * 4);
    float* s_in    = (float*)alloc(N_NODES * 4);
    float* y1      = (float*)alloc((size_t)N_NODES * DIM1 * 4);  // reused as y2
    float* agg1    = (float*)alloc((size_t)N_NODES * DIM1 * 4);  // reused as agg2
    float* y2      = y1;
    float* agg2    = agg1;

    // zero the two histogram arrays (adjacent allocations would still have pad gaps; do both)
    hipMemsetAsync(cnt_out, 0, N_NODES * 4, stream);
    hipMemsetAsync(cnt_in, 0, N_NODES * 4, stream);

    k_hist<<<(N_EDGES + 255) / 256, 256, 0, stream>>>(src, dst, cnt_out, cnt_in, pos);
    k_scan<<<1, 1024, 0, stream>>>(cnt_in, row_ptr);
    k_scatter<<<(N_EDGES + 255) / 256, 256, 0, stream>>>(src, dst, row_ptr, pos, esrc);
    k_scales<<<(N_NODES + 255) / 256, 256, 0, stream>>>(cnt_out, cnt_in, s_out, s_in);

    dim3 g1(DIM1 / 64, (N_NODES + 63) / 64);
    k_gemm1<<<g1, 256, 0, stream>>>(feat, s_out, W1, y1);
    k_agg256<<<N_NODES / 4, 256, 0, stream>>>(row_ptr, esrc, y1, agg1);

    dim3 g2(DIM2 / 64, (N_NODES + 63) / 64);
    k_gemm2<<<g2, 256, 0, stream>>>(agg1, s_in, s_out, b1, W2, y2);
    k_agg128<<<N_NODES / 4, 256, 0, stream>>>(row_ptr, esrc, y2, agg2);

    k_head<<<N_NODES / 4, 256, 0, stream>>>(agg2, s_in, b2, Wo1, bo1, Wo2, bo2, out);
}

// Round 2
// 1510.057 us; speedup vs baseline: 1.3112x; 1.3112x over previous
//
#include <hip/hip_runtime.h>
#include <hip/hip_bf16.h>
#include <hip/hip_fp16.h>

#define N_NODES 100000
#define N_EDGES 3200000
#define DIM0 512   // IN_DIM * N_SEQ
#define DIM1 256   // HID1
#define DIM2 128   // HID2
#define DIM3 64    // END
#define NSB 98     // ceil(N_NODES / 1024)

// ---------------- CSR build ----------------

__global__ __launch_bounds__(256) void k_hist(const int* __restrict__ src,
                                              const int* __restrict__ dst,
                                              int* __restrict__ cnt_out,
                                              int* __restrict__ cnt_in,
                                              int* __restrict__ pos) {
    int e = blockIdx.x * 256 + threadIdx.x;
    if (e < N_EDGES) {
        atomicAdd(&cnt_out[src[e]], 1);
        pos[e] = atomicAdd(&cnt_in[dst[e]], 1);
    }
}

// hierarchical scan: per-block exclusive prefix + block sums
__global__ __launch_bounds__(1024) void k_scan_a(const int* __restrict__ cnt,
                                                 int* __restrict__ excl,
                                                 int* __restrict__ bsum) {
    __shared__ int buf[1024];
    int tid = threadIdx.x;
    int i = blockIdx.x * 1024 + tid;
    int v = (i < N_NODES) ? cnt[i] : 0;
    buf[tid] = v;
    __syncthreads();
    #pragma unroll
    for (int off = 1; off < 1024; off <<= 1) {
        int t = (tid >= off) ? buf[tid - off] : 0;
        __syncthreads();
        buf[tid] += t;
        __syncthreads();
    }
    if (i < N_NODES) excl[i] = buf[tid] - v;
    if (tid == 1023) bsum[blockIdx.x] = buf[1023];
}

__global__ __launch_bounds__(128) void k_scan_b(const int* __restrict__ bsum,
                                                int* __restrict__ boff) {
    __shared__ int buf[128];
    int tid = threadIdx.x;
    int v = (tid < NSB) ? bsum[tid] : 0;
    buf[tid] = v;
    __syncthreads();
    #pragma unroll
    for (int off = 1; off < 128; off <<= 1) {
        int t = (tid >= off) ? buf[tid - off] : 0;
        __syncthreads();
        buf[tid] += t;
        __syncthreads();
    }
    if (tid < NSB) boff[tid] = buf[tid] - v;
    if (tid == 127) boff[NSB] = buf[127];
}

__global__ __launch_bounds__(256) void k_scan_c(const int* __restrict__ excl,
                                                const int* __restrict__ boff,
                                                int* __restrict__ row_ptr) {
    int i = blockIdx.x * 256 + threadIdx.x;
    if (i < N_NODES) row_ptr[i] = excl[i] + boff[i >> 10];
    if (i == 0) row_ptr[N_NODES] = boff[NSB];
}

__global__ __launch_bounds__(256) void k_scatter(const int* __restrict__ src,
                                                 const int* __restrict__ dst,
                                                 const int* __restrict__ row_ptr,
                                                 const int* __restrict__ pos,
                                                 int* __restrict__ esrc) {
    int e = blockIdx.x * 256 + threadIdx.x;
    if (e < N_EDGES) esrc[row_ptr[dst[e]] + pos[e]] = src[e];
}

__global__ __launch_bounds__(256) void k_scales(const int* __restrict__ cnt_out,
                                                const int* __restrict__ cnt_in,
                                                float* __restrict__ s_out,
                                                float* __restrict__ s_in) {
    int i = blockIdx.x * 256 + threadIdx.x;
    if (i < N_NODES) {
        int co = cnt_out[i]; if (co < 1) co = 1;
        int ci = cnt_in[i];  if (ci < 1) ci = 1;
        s_out[i] = rsqrtf((float)co);
        s_in[i]  = rsqrtf((float)ci);
    }
}

// ---------------- GEMM1: y1 = (feat * s_out) @ W1, fp32 compute, fp16 output ----

__global__ __launch_bounds__(256) void k_gemm1(const float* __restrict__ feat,
                                               const float* __restrict__ s_out,
                                               const float* __restrict__ W,
                                               __half* __restrict__ y) {
    __shared__ float As[16][65];   // [k][n]
    __shared__ float Bs[16][64];   // [k][m]
    int tid = threadIdx.x;
    int tx = tid & 15, ty = tid >> 4;
    int n0 = blockIdx.y * 64;
    int m0 = blockIdx.x * 64;

    int arow = tid >> 2, acol0 = (tid & 3) * 4;
    int an = n0 + arow;
    float ascale = (an < N_NODES) ? s_out[an] : 0.0f;
    int an_c = (an < N_NODES) ? an : (N_NODES - 1);
    const float* aptr = feat + (size_t)an_c * DIM0 + acol0;
    const float* bptr = W + ty * DIM1 + m0 + tx * 4;

    float c[4][4] = {};
    for (int k0 = 0; k0 < DIM0; k0 += 16) {
        float4 av = *(const float4*)(aptr + k0);
        float4 bv = *(const float4*)(bptr + (size_t)k0 * DIM1);
        __syncthreads();
        As[acol0 + 0][arow] = av.x * ascale;
        As[acol0 + 1][arow] = av.y * ascale;
        As[acol0 + 2][arow] = av.z * ascale;
        As[acol0 + 3][arow] = av.w * ascale;
        *(float4*)&Bs[ty][tx * 4] = bv;
        __syncthreads();
        #pragma unroll
        for (int k = 0; k < 16; ++k) {
            float a0 = As[k][ty * 4 + 0];
            float a1 = As[k][ty * 4 + 1];
            float a2 = As[k][ty * 4 + 2];
            float a3 = As[k][ty * 4 + 3];
            float4 b = *(const float4*)&Bs[k][tx * 4];
            c[0][0] += a0 * b.x; c[0][1] += a0 * b.y; c[0][2] += a0 * b.z; c[0][3] += a0 * b.w;
            c[1][0] += a1 * b.x; c[1][1] += a1 * b.y; c[1][2] += a1 * b.z; c[1][3] += a1 * b.w;
            c[2][0] += a2 * b.x; c[2][1] += a2 * b.y; c[2][2] += a2 * b.z; c[2][3] += a2 * b.w;
            c[3][0] += a3 * b.x; c[3][1] += a3 * b.y; c[3][2] += a3 * b.z; c[3][3] += a3 * b.w;
        }
    }
    #pragma unroll
    for (int i = 0; i < 4; ++i) {
        int n = n0 + ty * 4 + i;
        if (n < N_NODES) {
            union { uint2 u; __half2 h[2]; } cv;
            cv.h[0] = __floats2half2_rn(c[i][0], c[i][1]);
            cv.h[1] = __floats2half2_rn(c[i][2], c[i][3]);
            *(uint2*)&y[(size_t)n * DIM1 + m0 + tx * 4] = cv.u;
        }
    }
}

// ---------------- aggregation dim=256 (fp16 payload): one wave per dst node ------

__global__ __launch_bounds__(256) void k_agg256(const int* __restrict__ row_ptr,
                                                const int* __restrict__ esrc,
                                                const __half* __restrict__ y1,
                                                __half* __restrict__ agg) {
    int wave = threadIdx.x >> 6;
    int lane = threadIdx.x & 63;
    int n = blockIdx.x * 4 + wave;   // 25000 * 4 = 100000 exact
    int beg = row_ptr[n], end = row_ptr[n + 1];
    const uint2* ybase = (const uint2*)y1;   // 4 halves per uint2; 64 per row
    float4 acc = make_float4(0.f, 0.f, 0.f, 0.f);
    int i = beg;
    for (; i + 4 <= end; i += 4) {
        int s0 = esrc[i], s1 = esrc[i + 1], s2 = esrc[i + 2], s3 = esrc[i + 3];
        uint2 r0 = ybase[(size_t)s0 * 64 + lane];
        uint2 r1 = ybase[(size_t)s1 * 64 + lane];
        uint2 r2 = ybase[(size_t)s2 * 64 + lane];
        uint2 r3 = ybase[(size_t)s3 * 64 + lane];
        float2 a0 = __half22float2(*(__half2*)&r0.x), b0 = __half22float2(*(__half2*)&r0.y);
        float2 a1 = __half22float2(*(__half2*)&r1.x), b1 = __half22float2(*(__half2*)&r1.y);
        float2 a2 = __half22float2(*(__half2*)&r2.x), b2 = __half22float2(*(__half2*)&r2.y);
        float2 a3 = __half22float2(*(__half2*)&r3.x), b3 = __half22float2(*(__half2*)&r3.y);
        acc.x += a0.x + a1.x + a2.x + a3.x;
        acc.y += a0.y + a1.y + a2.y + a3.y;
        acc.z += b0.x + b1.x + b2.x + b3.x;
        acc.w += b0.y + b1.y + b2.y + b3.y;
    }
    for (; i < end; ++i) {
        uint2 r = ybase[(size_t)esrc[i] * 64 + lane];
        float2 a = __half22float2(*(__half2*)&r.x), b = __half22float2(*(__half2*)&r.y);
        acc.x += a.x; acc.y += a.y; acc.z += b.x; acc.w += b.y;
    }
    union { uint2 u; __half2 h[2]; } cv;
    cv.h[0] = __floats2half2_rn(acc.x, acc.y);
    cv.h[1] = __floats2half2_rn(acc.z, acc.w);
    *(uint2*)&agg[(size_t)n * DIM1 + lane * 4] = cv.u;
}

// ---- GEMM2: y2 = (relu(agg1*s_in+b1) * s_out) @ W2, fp16 A + output, fp32 compute

__global__ __launch_bounds__(256) void k_gemm2(const __half* __restrict__ agg1,
                                               const float* __restrict__ s_in,
                                               const float* __restrict__ s_out,
                                               const float* __restrict__ b1,
                                               const float* __restrict__ W,
                                               __half* __restrict__ y) {
    __shared__ float As[16][65];
    __shared__ float Bs[16][64];
    int tid = threadIdx.x;
    int tx = tid & 15, ty = tid >> 4;
    int n0 = blockIdx.y * 64;
    int m0 = blockIdx.x * 64;

    int arow = tid >> 2, acol0 = (tid & 3) * 4;
    int an = n0 + arow;
    bool valid = (an < N_NODES);
    int an_c = valid ? an : (N_NODES - 1);
    float si = valid ? s_in[an] : 0.0f;
    float so = valid ? s_out[an] : 0.0f;
    const __half* aptr = agg1 + (size_t)an_c * DIM1 + acol0;
    const float* bptr = W + ty * DIM2 + m0 + tx * 4;

    float c[4][4] = {};
    for (int k0 = 0; k0 < DIM1; k0 += 16) {
        uint2 au = *(const uint2*)(aptr + k0);
        float2 a01 = __half22float2(*(__half2*)&au.x);
        float2 a23 = __half22float2(*(__half2*)&au.y);
        float4 bb = *(const float4*)(b1 + k0 + acol0);
        float4 bv = *(const float4*)(bptr + (size_t)k0 * DIM2);
        float4 av;
        av.x = fmaxf(a01.x * si + bb.x, 0.f) * so;
        av.y = fmaxf(a01.y * si + bb.y, 0.f) * so;
        av.z = fmaxf(a23.x * si + bb.z, 0.f) * so;
        av.w = fmaxf(a23.y * si + bb.w, 0.f) * so;
        __syncthreads();
        As[acol0 + 0][arow] = av.x;
        As[acol0 + 1][arow] = av.y;
        As[acol0 + 2][arow] = av.z;
        As[acol0 + 3][arow] = av.w;
        *(float4*)&Bs[ty][tx * 4] = bv;
        __syncthreads();
        #pragma unroll
        for (int k = 0; k < 16; ++k) {
            float a0 = As[k][ty * 4 + 0];
            float a1 = As[k][ty * 4 + 1];
            float a2 = As[k][ty * 4 + 2];
            float a3 = As[k][ty * 4 + 3];
            float4 b = *(const float4*)&Bs[k][tx * 4];
            c[0][0] += a0 * b.x; c[0][1] += a0 * b.y; c[0][2] += a0 * b.z; c[0][3] += a0 * b.w;
            c[1][0] += a1 * b.x; c[1][1] += a1 * b.y; c[1][2] += a1 * b.z; c[1][3] += a1 * b.w;
            c[2][0] += a2 * b.x; c[2][1] += a2 * b.y; c[2][2] += a2 * b.z; c[2][3] += a2 * b.w;
            c[3][0] += a3 * b.x; c[3][1] += a3 * b.y; c[3][2] += a3 * b.z; c[3][3] += a3 * b.w;
        }
    }
    #pragma unroll
    for (int i = 0; i < 4; ++i) {
        int n = n0 + ty * 4 + i;
        if (n < N_NODES) {
            union { uint2 u; __half2 h[2]; } cv;
            cv.h[0] = __floats2half2_rn(c[i][0], c[i][1]);
            cv.h[1] = __floats2half2_rn(c[i][2], c[i][3]);
            *(uint2*)&y[(size_t)n * DIM2 + m0 + tx * 4] = cv.u;
        }
    }
}

// ---- fused aggregation dim=128 (fp16 payload) + MLP head, one wave per node ----

__global__ __launch_bounds__(256) void k_agg_head(const int* __restrict__ row_ptr,
                                                  const int* __restrict__ esrc,
                                                  const __half* __restrict__ y2,
                                                  const float* __restrict__ s_in,
                                                  const float* __restrict__ b2,
                                                  const float* __restrict__ Wo1,
                                                  const float* __restrict__ bo1,
                                                  const float* __restrict__ Wo2,
                                                  const float* __restrict__ bo2,
                                                  float* __restrict__ out) {
    __shared__ float w1s[DIM2 * DIM3];   // 32 KB
    __shared__ float w2s[DIM3];
    __shared__ float hs[4][DIM2];
    int tid = threadIdx.x;
    for (int i = tid; i < DIM2 * DIM3; i += 256) w1s[i] = Wo1[i];
    if (tid < DIM3) w2s[tid] = Wo2[tid];
    __syncthreads();

    int wave = tid >> 6, lane = tid & 63;
    int n = blockIdx.x * 4 + wave;
    int beg = row_ptr[n], end = row_ptr[n + 1];
    const unsigned* ybase = (const unsigned*)y2;   // half2 per uint; 64 per row
    float2 acc = make_float2(0.f, 0.f);
    int i = beg;
    for (; i + 4 <= end; i += 4) {
        unsigned r0 = ybase[(size_t)esrc[i] * 64 + lane];
        unsigned r1 = ybase[(size_t)esrc[i + 1] * 64 + lane];
        unsigned r2 = ybase[(size_t)esrc[i + 2] * 64 + lane];
        unsigned r3 = ybase[(size_t)esrc[i + 3] * 64 + lane];
        float2 f0 = __half22float2(*(__half2*)&r0);
        float2 f1 = __half22float2(*(__half2*)&r1);
        float2 f2 = __half22float2(*(__half2*)&r2);
        float2 f3 = __half22float2(*(__half2*)&r3);
        acc.x += f0.x + f1.x + f2.x + f3.x;
        acc.y += f0.y + f1.y + f2.y + f3.y;
    }
    for (; i < end; ++i) {
        unsigned r = ybase[(size_t)esrc[i] * 64 + lane];
        float2 f = __half22float2(*(__half2*)&r);
        acc.x += f.x; acc.y += f.y;
    }
    float si = s_in[n];
    float2 bv = *(const float2*)&b2[lane * 2];
    hs[wave][lane * 2 + 0] = acc.x * si + bv.x;
    hs[wave][lane * 2 + 1] = acc.y * si + bv.y;
    __syncthreads();

    float t = bo1[lane];
    #pragma unroll 8
    for (int k = 0; k < DIM2; ++k) t += hs[wave][k] * w1s[k * DIM3 + lane];
    t = fmaxf(t, 0.f);
    float p = t * w2s[lane];
    #pragma unroll
    for (int off = 32; off > 0; off >>= 1) p += __shfl_down(p, off);
    if (lane == 0) out[n] = p + bo2[0];
}

// ---------------- launch ----------------

extern "C" void kernel_launch(void* const* d_in, const int* in_sizes, int n_in,
                              void* d_out, int out_size, void* d_ws, size_t ws_size,
                              hipStream_t stream) {
    const float* feat = (const float*)d_in[0];
    const int*   src  = (const int*)d_in[1];
    const int*   dst  = (const int*)d_in[2];
    const float* W1   = (const float*)d_in[3];
    const float* b1   = (const float*)d_in[4];
    const float* W2   = (const float*)d_in[5];
    const float* b2   = (const float*)d_in[6];
    const float* Wo1  = (const float*)d_in[7];
    const float* bo1  = (const float*)d_in[8];
    const float* Wo2  = (const float*)d_in[9];
    const float* bo2  = (const float*)d_in[10];
    float* out = (float*)d_out;

    char* ws = (char*)d_ws;
    size_t off = 0;
    auto alloc = [&](size_t bytes) -> char* {
        char* p = ws + off;
        off = (off + bytes + 255) & ~(size_t)255;
        return p;
    };
    int*    cnt_out = (int*)alloc(N_NODES * 4);
    int*    cnt_in  = (int*)alloc(N_NODES * 4);
    int*    row_ptr = (int*)alloc((N_NODES + 1) * 4);
    int*    excl    = (int*)alloc(N_NODES * 4);
    int*    bsum    = (int*)alloc((NSB + 1) * 4);
    int*    boff    = (int*)alloc((NSB + 1) * 4);
    int*    pos     = (int*)alloc((size_t)N_EDGES * 4);
    int*    esrc    = (int*)alloc((size_t)N_EDGES * 4);
    float*  s_out   = (float*)alloc(N_NODES * 4);
    float*  s_in    = (float*)alloc(N_NODES * 4);
    __half* y1h     = (__half*)alloc((size_t)N_NODES * DIM1 * 2);
    __half* agg1h   = (__half*)alloc((size_t)N_NODES * DIM1 * 2);
    __half* y2h     = (__half*)alloc((size_t)N_NODES * DIM2 * 2);

    hipMemsetAsync(cnt_out, 0, N_NODES * 4, stream);
    hipMemsetAsync(cnt_in, 0, N_NODES * 4, stream);

    k_hist<<<(N_EDGES + 255) / 256, 256, 0, stream>>>(src, dst, cnt_out, cnt_in, pos);
    k_scan_a<<<NSB, 1024, 0, stream>>>(cnt_in, excl, bsum);
    k_scan_b<<<1, 128, 0, stream>>>(bsum, boff);
    k_scan_c<<<(N_NODES + 255) / 256, 256, 0, stream>>>(excl, boff, row_ptr);
    k_scatter<<<(N_EDGES + 255) / 256, 256, 0, stream>>>(src, dst, row_ptr, pos, esrc);
    k_scales<<<(N_NODES + 255) / 256, 256, 0, stream>>>(cnt_out, cnt_in, s_out, s_in);

    dim3 g1(DIM1 / 64, (N_NODES + 63) / 64);
    k_gemm1<<<g1, 256, 0, stream>>>(feat, s_out, W1, y1h);
    k_agg256<<<N_NODES / 4, 256, 0, stream>>>(row_ptr, esrc, y1h, agg1h);

    dim3 g2(DIM2 / 64, (N_NODES + 63) / 64);
    k_gemm2<<<g2, 256, 0, stream>>>(agg1h, s_in, s_out, b1, W2, y2h);
    k_agg_head<<<N_NODES / 4, 256, 0, stream>>>(row_ptr, esrc, y2h, s_in, b2,
                                                Wo1, bo1, Wo2, bo2, out);
}

// Round 3
// 1171.613 us; speedup vs baseline: 1.6900x; 1.2889x over previous
//
#include <hip/hip_runtime.h>
#include <hip/hip_bf16.h>
#include <hip/hip_fp16.h>

#define N_NODES 100000
#define N_EDGES 3200000
#define DIM0 512   // IN_DIM * N_SEQ
#define DIM1 256   // HID1
#define DIM2 128   // HID2
#define DIM3 64    // END
#define NSB 98     // ceil(N_NODES / 1024)

typedef _Float16 f16x8 __attribute__((ext_vector_type(8)));
typedef float f32x4 __attribute__((ext_vector_type(4)));

// ---------------- CSR build ----------------

__global__ __launch_bounds__(256) void k_hist(const int* __restrict__ src,
                                              const int* __restrict__ dst,
                                              int* __restrict__ cnt_out,
                                              int* __restrict__ cnt_in,
                                              int* __restrict__ pos) {
    int e = blockIdx.x * 256 + threadIdx.x;
    if (e < N_EDGES) {
        atomicAdd(&cnt_out[src[e]], 1);
        pos[e] = atomicAdd(&cnt_in[dst[e]], 1);
    }
}

__global__ __launch_bounds__(1024) void k_scan_a(const int* __restrict__ cnt,
                                                 int* __restrict__ excl,
                                                 int* __restrict__ bsum) {
    __shared__ int buf[1024];
    int tid = threadIdx.x;
    int i = blockIdx.x * 1024 + tid;
    int v = (i < N_NODES) ? cnt[i] : 0;
    buf[tid] = v;
    __syncthreads();
    #pragma unroll
    for (int off = 1; off < 1024; off <<= 1) {
        int t = (tid >= off) ? buf[tid - off] : 0;
        __syncthreads();
        buf[tid] += t;
        __syncthreads();
    }
    if (i < N_NODES) excl[i] = buf[tid] - v;
    if (tid == 1023) bsum[blockIdx.x] = buf[1023];
}

__global__ __launch_bounds__(128) void k_scan_b(const int* __restrict__ bsum,
                                                int* __restrict__ boff) {
    __shared__ int buf[128];
    int tid = threadIdx.x;
    int v = (tid < NSB) ? bsum[tid] : 0;
    buf[tid] = v;
    __syncthreads();
    #pragma unroll
    for (int off = 1; off < 128; off <<= 1) {
        int t = (tid >= off) ? buf[tid - off] : 0;
        __syncthreads();
        buf[tid] += t;
        __syncthreads();
    }
    if (tid < NSB) boff[tid] = buf[tid] - v;
    if (tid == 127) boff[NSB] = buf[127];
}

__global__ __launch_bounds__(256) void k_scan_c(const int* __restrict__ excl,
                                                const int* __restrict__ boff,
                                                int* __restrict__ row_ptr) {
    int i = blockIdx.x * 256 + threadIdx.x;
    if (i < N_NODES) row_ptr[i] = excl[i] + boff[i >> 10];
    if (i == 0) row_ptr[N_NODES] = boff[NSB];
}

__global__ __launch_bounds__(256) void k_scatter(const int* __restrict__ src,
                                                 const int* __restrict__ dst,
                                                 const int* __restrict__ row_ptr,
                                                 const int* __restrict__ pos,
                                                 int* __restrict__ esrc) {
    int e = blockIdx.x * 256 + threadIdx.x;
    if (e < N_EDGES) esrc[row_ptr[dst[e]] + pos[e]] = src[e];
}

__global__ __launch_bounds__(256) void k_scales(const int* __restrict__ cnt_out,
                                                const int* __restrict__ cnt_in,
                                                float* __restrict__ s_out,
                                                float* __restrict__ s_in) {
    int i = blockIdx.x * 256 + threadIdx.x;
    if (i < N_NODES) {
        int co = cnt_out[i]; if (co < 1) co = 1;
        int ci = cnt_in[i];  if (ci < 1) ci = 1;
        s_out[i] = rsqrtf((float)co);
        s_in[i]  = rsqrtf((float)ci);
    }
}

// ---------------- weight convert + transpose (tiny) ----------------

__global__ __launch_bounds__(256) void k_cvtW1(const float* __restrict__ W1,
                                               __half* __restrict__ W1t) {
    int idx = blockIdx.x * 256 + threadIdx.x;      // over 512*256, reads coalesced
    if (idx < DIM0 * DIM1) {
        int k = idx / DIM1, n = idx % DIM1;
        W1t[n * DIM0 + k] = __float2half(W1[idx]); // [256][512]
    }
}

__global__ __launch_bounds__(256) void k_cvtW2(const float* __restrict__ W2,
                                               __half* __restrict__ W2t) {
    int idx = blockIdx.x * 256 + threadIdx.x;      // over 256*128
    if (idx < DIM1 * DIM2) {
        int k = idx / DIM2, n = idx % DIM2;
        W2t[n * DIM1 + k] = __float2half(W2[idx]); // [128][256]
    }
}

// ---- GEMM1 (MFMA fp16): y1 = fp16((feat * s_out) @ W1), tile 64 x 256(full), BK=32

__global__ __launch_bounds__(256) void k_gemm1(const float* __restrict__ feat,
                                               const float* __restrict__ s_out,
                                               const __half* __restrict__ W1t,
                                               __half* __restrict__ y) {
    __shared__ __align__(16) _Float16 As[64][40];    // 64 rows x 32k (+8 pad)
    __shared__ __align__(16) _Float16 Bs[256][40];   // 256 cols x 32k (+8 pad)
    int tid = threadIdx.x;
    int wv = tid >> 6, lane = tid & 63;
    int m16 = lane & 15, quad = lane >> 4;
    int n0 = blockIdx.x * 64;

    // A staging coords: thread -> (row, 8-float k chunk)
    int srow = tid >> 2;
    int scol = (tid & 3) * 8;
    int gr = n0 + srow;
    bool avalid = gr < N_NODES;
    int grc = avalid ? gr : (N_NODES - 1);
    float ascale = avalid ? s_out[gr] : 0.0f;
    const float* aptr = feat + (size_t)grc * DIM0 + scol;
    // B staging coords: 4 passes x (64 rows x 4 chunks)
    int bn = tid >> 2;
    int bc = (tid & 3) * 8;

    f32x4 acc[4][4] = {};
    for (int k0 = 0; k0 < DIM0; k0 += 32) {
        float4 f0 = *(const float4*)(aptr + k0);
        float4 f1 = *(const float4*)(aptr + k0 + 4);
        __syncthreads();
        {
            f16x8 h;
            h[0] = (_Float16)(f0.x * ascale); h[1] = (_Float16)(f0.y * ascale);
            h[2] = (_Float16)(f0.z * ascale); h[3] = (_Float16)(f0.w * ascale);
            h[4] = (_Float16)(f1.x * ascale); h[5] = (_Float16)(f1.y * ascale);
            h[6] = (_Float16)(f1.z * ascale); h[7] = (_Float16)(f1.w * ascale);
            *(f16x8*)&As[srow][scol] = h;
        }
        #pragma unroll
        for (int p = 0; p < 4; ++p) {
            int n = p * 64 + bn;
            f16x8 v = *(const f16x8*)(W1t + (size_t)n * DIM0 + k0 + bc);
            *(f16x8*)&Bs[n][bc] = v;
        }
        __syncthreads();
        f16x8 af[4], bf[4];
        #pragma unroll
        for (int r = 0; r < 4; ++r) af[r] = *(const f16x8*)&As[r * 16 + m16][quad * 8];
        #pragma unroll
        for (int c = 0; c < 4; ++c) bf[c] = *(const f16x8*)&Bs[wv * 64 + c * 16 + m16][quad * 8];
        #pragma unroll
        for (int r = 0; r < 4; ++r)
            #pragma unroll
            for (int c = 0; c < 4; ++c)
                acc[r][c] = __builtin_amdgcn_mfma_f32_16x16x32_f16(af[r], bf[c], acc[r][c], 0, 0, 0);
    }
    #pragma unroll
    for (int r = 0; r < 4; ++r) {
        #pragma unroll
        for (int i = 0; i < 4; ++i) {
            int row = n0 + r * 16 + quad * 4 + i;
            if (row < N_NODES) {
                #pragma unroll
                for (int c = 0; c < 4; ++c) {
                    int col = wv * 64 + c * 16 + m16;
                    y[(size_t)row * DIM1 + col] = __float2half(acc[r][c][i]);
                }
            }
        }
    }
}

// ---- aggregation dim=256 (fp16 payload) + fused relu(x*s_in+b1)*s_out epilogue ----

__global__ __launch_bounds__(256) void k_agg256(const int* __restrict__ row_ptr,
                                                const int* __restrict__ esrc,
                                                const __half* __restrict__ y1,
                                                const float* __restrict__ s_in,
                                                const float* __restrict__ s_out,
                                                const float* __restrict__ b1,
                                                __half* __restrict__ x2) {
    int wave = threadIdx.x >> 6;
    int lane = threadIdx.x & 63;
    int n = blockIdx.x * 4 + wave;   // 25000 * 4 = 100000 exact
    int beg = row_ptr[n], end = row_ptr[n + 1];
    const uint2* ybase = (const uint2*)y1;   // 4 halves per uint2; 64 per row
    float4 acc = make_float4(0.f, 0.f, 0.f, 0.f);
    int i = beg;
    for (; i + 4 <= end; i += 4) {
        int s0 = esrc[i], s1 = esrc[i + 1], s2 = esrc[i + 2], s3 = esrc[i + 3];
        uint2 r0 = ybase[(size_t)s0 * 64 + lane];
        uint2 r1 = ybase[(size_t)s1 * 64 + lane];
        uint2 r2 = ybase[(size_t)s2 * 64 + lane];
        uint2 r3 = ybase[(size_t)s3 * 64 + lane];
        float2 a0 = __half22float2(*(__half2*)&r0.x), b0 = __half22float2(*(__half2*)&r0.y);
        float2 a1 = __half22float2(*(__half2*)&r1.x), b1v = __half22float2(*(__half2*)&r1.y);
        float2 a2 = __half22float2(*(__half2*)&r2.x), b2v = __half22float2(*(__half2*)&r2.y);
        float2 a3 = __half22float2(*(__half2*)&r3.x), b3v = __half22float2(*(__half2*)&r3.y);
        acc.x += a0.x + a1.x + a2.x + a3.x;
        acc.y += a0.y + a1.y + a2.y + a3.y;
        acc.z += b0.x + b1v.x + b2v.x + b3v.x;
        acc.w += b0.y + b1v.y + b2v.y + b3v.y;
    }
    for (; i < end; ++i) {
        uint2 r = ybase[(size_t)esrc[i] * 64 + lane];
        float2 a = __half22float2(*(__half2*)&r.x), b = __half22float2(*(__half2*)&r.y);
        acc.x += a.x; acc.y += a.y; acc.z += b.x; acc.w += b.y;
    }
    float si = s_in[n];
    float so = s_out[n];
    float4 bb = *(const float4*)&b1[lane * 4];
    acc.x = fmaxf(acc.x * si + bb.x, 0.f) * so;
    acc.y = fmaxf(acc.y * si + bb.y, 0.f) * so;
    acc.z = fmaxf(acc.z * si + bb.z, 0.f) * so;
    acc.w = fmaxf(acc.w * si + bb.w, 0.f) * so;
    union { uint2 u; __half2 h[2]; } cv;
    cv.h[0] = __floats2half2_rn(acc.x, acc.y);
    cv.h[1] = __floats2half2_rn(acc.z, acc.w);
    *(uint2*)&x2[(size_t)n * DIM1 + lane * 4] = cv.u;
}

// ---- GEMM2 (MFMA fp16): y2 = fp16(x2 @ W2), tile 64 x 128(full), BK=32 ----

__global__ __launch_bounds__(256) void k_gemm2(const __half* __restrict__ x2,
                                               const __half* __restrict__ W2t,
                                               __half* __restrict__ y) {
    __shared__ __align__(16) _Float16 As[64][40];
    __shared__ __align__(16) _Float16 Bs[128][40];
    int tid = threadIdx.x;
    int wv = tid >> 6, lane = tid & 63;
    int m16 = lane & 15, quad = lane >> 4;
    int n0 = blockIdx.x * 64;

    int srow = tid >> 2;
    int scol = (tid & 3) * 8;
    int gr = n0 + srow;
    int grc = (gr < N_NODES) ? gr : (N_NODES - 1);
    const __half* aptr = x2 + (size_t)grc * DIM1 + scol;
    int bn = tid >> 2;
    int bc = (tid & 3) * 8;

    f32x4 acc[4][2] = {};
    for (int k0 = 0; k0 < DIM1; k0 += 32) {
        f16x8 av = *(const f16x8*)(aptr + k0);
        __syncthreads();
        *(f16x8*)&As[srow][scol] = av;
        #pragma unroll
        for (int p = 0; p < 2; ++p) {
            int n = p * 64 + bn;
            f16x8 v = *(const f16x8*)(W2t + (size_t)n * DIM1 + k0 + bc);
            *(f16x8*)&Bs[n][bc] = v;
        }
        __syncthreads();
        f16x8 af[4], bf[2];
        #pragma unroll
        for (int r = 0; r < 4; ++r) af[r] = *(const f16x8*)&As[r * 16 + m16][quad * 8];
        #pragma unroll
        for (int c = 0; c < 2; ++c) bf[c] = *(const f16x8*)&Bs[wv * 32 + c * 16 + m16][quad * 8];
        #pragma unroll
        for (int r = 0; r < 4; ++r)
            #pragma unroll
            for (int c = 0; c < 2; ++c)
                acc[r][c] = __builtin_amdgcn_mfma_f32_16x16x32_f16(af[r], bf[c], acc[r][c], 0, 0, 0);
    }
    #pragma unroll
    for (int r = 0; r < 4; ++r) {
        #pragma unroll
        for (int i = 0; i < 4; ++i) {
            int row = n0 + r * 16 + quad * 4 + i;
            if (row < N_NODES) {
                #pragma unroll
                for (int c = 0; c < 2; ++c) {
                    int col = wv * 32 + c * 16 + m16;
                    y[(size_t)row * DIM2 + col] = __float2half(acc[r][c][i]);
                }
            }
        }
    }
}

// ---- fused aggregation dim=128 (fp16 payload) + MLP head, one wave per node ----

__global__ __launch_bounds__(256) void k_agg_head(const int* __restrict__ row_ptr,
                                                  const int* __restrict__ esrc,
                                                  const __half* __restrict__ y2,
                                                  const float* __restrict__ s_in,
                                                  const float* __restrict__ b2,
                                                  const float* __restrict__ Wo1,
                                                  const float* __restrict__ bo1,
                                                  const float* __restrict__ Wo2,
                                                  const float* __restrict__ bo2,
                                                  float* __restrict__ out) {
    __shared__ float w1s[DIM2 * DIM3];   // 32 KB
    __shared__ float w2s[DIM3];
    __shared__ float hs[4][DIM2];
    int tid = threadIdx.x;
    for (int i = tid; i < DIM2 * DIM3; i += 256) w1s[i] = Wo1[i];
    if (tid < DIM3) w2s[tid] = Wo2[tid];
    __syncthreads();

    int wave = tid >> 6, lane = tid & 63;
    int n = blockIdx.x * 4 + wave;
    int beg = row_ptr[n], end = row_ptr[n + 1];
    const unsigned* ybase = (const unsigned*)y2;   // half2 per uint; 64 per row
    float2 acc = make_float2(0.f, 0.f);
    int i = beg;
    for (; i + 4 <= end; i += 4) {
        unsigned r0 = ybase[(size_t)esrc[i] * 64 + lane];
        unsigned r1 = ybase[(size_t)esrc[i + 1] * 64 + lane];
        unsigned r2 = ybase[(size_t)esrc[i + 2] * 64 + lane];
        unsigned r3 = ybase[(size_t)esrc[i + 3] * 64 + lane];
        float2 f0 = __half22float2(*(__half2*)&r0);
        float2 f1 = __half22float2(*(__half2*)&r1);
        float2 f2 = __half22float2(*(__half2*)&r2);
        float2 f3 = __half22float2(*(__half2*)&r3);
        acc.x += f0.x + f1.x + f2.x + f3.x;
        acc.y += f0.y + f1.y + f2.y + f3.y;
    }
    for (; i < end; ++i) {
        unsigned r = ybase[(size_t)esrc[i] * 64 + lane];
        float2 f = __half22float2(*(__half2*)&r);
        acc.x += f.x; acc.y += f.y;
    }
    float si = s_in[n];
    float2 bv = *(const float2*)&b2[lane * 2];
    hs[wave][lane * 2 + 0] = acc.x * si + bv.x;
    hs[wave][lane * 2 + 1] = acc.y * si + bv.y;
    __syncthreads();

    float t = bo1[lane];
    #pragma unroll 8
    for (int k = 0; k < DIM2; ++k) t += hs[wave][k] * w1s[k * DIM3 + lane];
    t = fmaxf(t, 0.f);
    float p = t * w2s[lane];
    #pragma unroll
    for (int off = 32; off > 0; off >>= 1) p += __shfl_down(p, off);
    if (lane == 0) out[n] = p + bo2[0];
}

// ---------------- launch ----------------

extern "C" void kernel_launch(void* const* d_in, const int* in_sizes, int n_in,
                              void* d_out, int out_size, void* d_ws, size_t ws_size,
                              hipStream_t stream) {
    const float* feat = (const float*)d_in[0];
    const int*   src  = (const int*)d_in[1];
    const int*   dst  = (const int*)d_in[2];
    const float* W1   = (const float*)d_in[3];
    const float* b1   = (const float*)d_in[4];
    const float* W2   = (const float*)d_in[5];
    const float* b2   = (const float*)d_in[6];
    const float* Wo1  = (const float*)d_in[7];
    const float* bo1  = (const float*)d_in[8];
    const float* Wo2  = (const float*)d_in[9];
    const float* bo2  = (const float*)d_in[10];
    float* out = (float*)d_out;

    char* ws = (char*)d_ws;
    size_t off = 0;
    auto alloc = [&](size_t bytes) -> char* {
        char* p = ws + off;
        off = (off + bytes + 255) & ~(size_t)255;
        return p;
    };
    int*    cnt_out = (int*)alloc(N_NODES * 4);
    int*    cnt_in  = (int*)alloc(N_NODES * 4);
    int*    row_ptr = (int*)alloc((N_NODES + 1) * 4);
    int*    excl    = (int*)alloc(N_NODES * 4);
    int*    bsum    = (int*)alloc((NSB + 1) * 4);
    int*    boff    = (int*)alloc((NSB + 1) * 4);
    int*    pos     = (int*)alloc((size_t)N_EDGES * 4);
    int*    esrc    = (int*)alloc((size_t)N_EDGES * 4);
    float*  s_out   = (float*)alloc(N_NODES * 4);
    float*  s_in    = (float*)alloc(N_NODES * 4);
    __half* W1t     = (__half*)alloc((size_t)DIM0 * DIM1 * 2);
    __half* W2t     = (__half*)alloc((size_t)DIM1 * DIM2 * 2);
    __half* y1h     = (__half*)alloc((size_t)N_NODES * DIM1 * 2);
    __half* x2h     = (__half*)alloc((size_t)N_NODES * DIM1 * 2);
    __half* y2h     = (__half*)alloc((size_t)N_NODES * DIM2 * 2);

    hipMemsetAsync(cnt_out, 0, N_NODES * 4, stream);
    hipMemsetAsync(cnt_in, 0, N_NODES * 4, stream);

    k_hist<<<(N_EDGES + 255) / 256, 256, 0, stream>>>(src, dst, cnt_out, cnt_in, pos);
    k_scan_a<<<NSB, 1024, 0, stream>>>(cnt_in, excl, bsum);
    k_scan_b<<<1, 128, 0, stream>>>(bsum, boff);
    k_scan_c<<<(N_NODES + 255) / 256, 256, 0, stream>>>(excl, boff, row_ptr);
    k_scatter<<<(N_EDGES + 255) / 256, 256, 0, stream>>>(src, dst, row_ptr, pos, esrc);
    k_scales<<<(N_NODES + 255) / 256, 256, 0, stream>>>(cnt_out, cnt_in, s_out, s_in);

    k_cvtW1<<<(DIM0 * DIM1 + 255) / 256, 256, 0, stream>>>(W1, W1t);
    k_cvtW2<<<(DIM1 * DIM2 + 255) / 256, 256, 0, stream>>>(W2, W2t);

    int nblk = (N_NODES + 63) / 64;
    k_gemm1<<<nblk, 256, 0, stream>>>(feat, s_out, W1t, y1h);
    k_agg256<<<N_NODES / 4, 256, 0, stream>>>(row_ptr, esrc, y1h, s_in, s_out, b1, x2h);
    k_gemm2<<<nblk, 256, 0, stream>>>(x2h, W2t, y2h);
    k_agg_head<<<N_NODES / 4, 256, 0, stream>>>(row_ptr, esrc, y2h, s_in, b2,
                                                Wo1, bo1, Wo2, bo2, out);
}